// Round 10
// baseline (692.343 us; speedup 1.0000x reference)
//
#include <hip/hip_runtime.h>

// GRU encoder: B=64, T=512, F=64, H=256, D=64.
//   k1: xproj = x @ kernel + bias -> f16 in d_ws (dot2 GEMM, unchanged).
//   k2: MFMA scan, 64 blocks x 1 batch x 512 threads (8 waves).
//       R9 evidence: step ~2765 cyc across ALL structures; VALUBusy says
//       ~860 cyc/step/SIMD of VALU — addressing overhead on the lockstep
//       critical path. R10 = VALU diet: saddr+imm-offset x-loads/stores
//       (scalar pointer bump per step), XOR ping-pong LDS addressing,
//       clamp-free prefetch (main 510 + epilogue 2), shorter gate chain.

typedef _Float16 half2_t __attribute__((ext_vector_type(2)));
typedef _Float16 f16x4_t __attribute__((ext_vector_type(4)));
typedef _Float16 f16x8_t __attribute__((ext_vector_type(8)));
typedef float f32x4_t __attribute__((ext_vector_type(4)));

#define LOG2E 1.4426950408889634f

__device__ __forceinline__ float fast_sigmoid(float x) {
  float e = __builtin_amdgcn_exp2f(-x * LOG2E);
  return __builtin_amdgcn_rcpf(1.0f + e);
}
__device__ __forceinline__ float fast_tanh(float x) {
  float e = __builtin_amdgcn_exp2f(x * (2.0f * LOG2E));
  return 1.0f - 2.0f * __builtin_amdgcn_rcpf(1.0f + e);
}

// LDS-only barrier: no vmcnt drain; global loads/stores pipeline across steps.
__device__ __forceinline__ void sync_lds() {
  asm volatile("s_waitcnt lgkmcnt(0)\n\ts_barrier" ::: "memory");
}

// ---------------------------------------------------------------------------
// Kernel 1: xproj GEMM.  C(32768x768) = A(32768x64) @ B(64x768) + bias.
// ---------------------------------------------------------------------------
__global__ __launch_bounds__(256, 4) void xproj_gemm(
    const float* __restrict__ x, const float* __restrict__ kmat,
    const float* __restrict__ bias, _Float16* __restrict__ xp) {
  __shared__ half2_t As2[32][132];  // [kpair][row]
  __shared__ half2_t Bs2[32][132];  // [kpair][col]
  const int tid = threadIdx.x;
  const int rb = blockIdx.x * 128;
  const int cb = blockIdx.y * 128;

  {
    const int k4 = (tid & 15) * 4;
    const int r0 = tid >> 4;
#pragma unroll
    for (int p = 0; p < 8; ++p) {
      int r = r0 + p * 16;
      float4 v = *(const float4*)(x + (size_t)(rb + r) * 64 + k4);
      half2_t lo, hi;
      lo[0] = (_Float16)v.x; lo[1] = (_Float16)v.y;
      hi[0] = (_Float16)v.z; hi[1] = (_Float16)v.w;
      As2[k4 / 2][r] = lo;
      As2[k4 / 2 + 1][r] = hi;
    }
  }
  {
    const int c4 = (tid & 31) * 4;
    const int kp0 = tid >> 5;
#pragma unroll
    for (int p = 0; p < 4; ++p) {
      int kp = kp0 + p * 8;
      float4 va = *(const float4*)(kmat + (size_t)(2 * kp) * 768 + cb + c4);
      float4 vb = *(const float4*)(kmat + (size_t)(2 * kp + 1) * 768 + cb + c4);
      half2_t o0, o1, o2, o3;
      o0[0] = (_Float16)va.x; o0[1] = (_Float16)vb.x;
      o1[0] = (_Float16)va.y; o1[1] = (_Float16)vb.y;
      o2[0] = (_Float16)va.z; o2[1] = (_Float16)vb.z;
      o3[0] = (_Float16)va.w; o3[1] = (_Float16)vb.w;
      Bs2[kp][c4 + 0] = o0;
      Bs2[kp][c4 + 1] = o1;
      Bs2[kp][c4 + 2] = o2;
      Bs2[kp][c4 + 3] = o3;
    }
  }
  __syncthreads();

  const int tx = tid & 15, ty = tid >> 4;
  const int r0 = ty * 8;
  const int c0 = tx * 4;
  float acc[8][8];
  {
    float4 b0 = *(const float4*)(bias + cb + c0);
    float4 b1 = *(const float4*)(bias + cb + 64 + c0);
    float bz[8] = {b0.x, b0.y, b0.z, b0.w, b1.x, b1.y, b1.z, b1.w};
#pragma unroll
    for (int i = 0; i < 8; ++i)
#pragma unroll
      for (int j = 0; j < 8; ++j) acc[i][j] = bz[j];
  }

#pragma unroll 2
  for (int kp = 0; kp < 32; ++kp) {
    half2_t a2[8], b2[8];
    *(int4*)(&a2[0]) = *(const int4*)(&As2[kp][r0]);
    *(int4*)(&a2[4]) = *(const int4*)(&As2[kp][r0 + 4]);
    *(int2*)(&b2[0]) = *(const int2*)(&Bs2[kp][c0]);
    *(int2*)(&b2[2]) = *(const int2*)(&Bs2[kp][c0 + 2]);
    *(int2*)(&b2[4]) = *(const int2*)(&Bs2[kp][64 + c0]);
    *(int2*)(&b2[6]) = *(const int2*)(&Bs2[kp][64 + c0 + 2]);
#pragma unroll
    for (int i = 0; i < 8; ++i)
#pragma unroll
      for (int j = 0; j < 8; ++j)
        acc[i][j] = __builtin_amdgcn_fdot2(a2[i], b2[j], acc[i][j], false);
  }

#pragma unroll
  for (int i = 0; i < 8; ++i) {
    f16x4_t o0, o1;
#pragma unroll
    for (int j = 0; j < 4; ++j) {
      o0[j] = (_Float16)acc[i][j];
      o1[j] = (_Float16)acc[i][4 + j];
    }
    _Float16* dst = xp + (size_t)(rb + r0 + i) * 768 + cb;
    *(f16x4_t*)(dst + c0) = o0;
    *(f16x4_t*)(dst + 64 + c0) = o1;
  }
}

// ---------------------------------------------------------------------------
// Kernel 2: MFMA GRU scan. 64 blocks = 64 batches, 512 thr = 8 waves.
// Wave w owns n-tiles {w+8i, i=0..5} (z,z,r,r,h,h); A-rows all carry h so
// every lane's acc[i][0] is rec for its column; gates in-lane, q==0 stores.
// ---------------------------------------------------------------------------
__global__ __launch_bounds__(512, 2) void gru_scan_mfma(
    const _Float16* __restrict__ xp, const float* __restrict__ wr,
    const float* __restrict__ dw, const float* __restrict__ db,
    float* __restrict__ out, float* __restrict__ state) {
  __shared__ alignas(16) _Float16 hA[2][256];  // h double-buffered (1 KiB)

  const int tid = threadIdx.x;
  const int b = blockIdx.x;  // batch
  const int w = tid >> 6;    // wave 0..7
  const int l = tid & 63;
  const int q = l >> 4;   // quad 0..3
  const int nl = l & 15;  // lane&15

  // --- B fragments: wave w covers n-tiles {w+8i} (z,z,r,r,h,h); lives in
  // AGPRs (MFMA-native, no move tax) per R9 measurement.
  f16x8_t wfrag[6][8];
#pragma unroll
  for (int i = 0; i < 6; ++i) {
    const int nt = w + 8 * i;
#pragma unroll
    for (int kt = 0; kt < 8; ++kt) {
      f16x8_t f;
#pragma unroll
      for (int j = 0; j < 8; ++j)
        f[j] = (_Float16)wr[(size_t)(kt * 32 + q * 8 + j) * 768 + nt * 16 + nl];
      wfrag[i][kt] = f;
    }
  }

  if (tid < 256) {
    hA[0][tid] = (_Float16)0.0f;
    hA[1][tid] = (_Float16)0.0f;
  }
  __syncthreads();

  const int col0 = w * 16 + nl;  // col group w (cols 0..127 across waves)
  // col1 = col0 + 128 expressed via immediate offsets below.
  float hold0 = 0.0f, hold1 = 0.0f;

  // Uniform-base pointers (advance by scalar add per step); lane offset is
  // folded into col0 once, +256/+512/+128/+384/+640 are immediate offsets.
  const _Float16* xr0 = xp + (size_t)b * 512 * 768 + col0;   // step t
  const _Float16* xr2 = xr0 + 2 * 768;                       // prefetch t+2
  float* orow = out + (size_t)b * 512 * 256 + col0;

  // LDS byte addresses, ping-ponged by ^512 each step.
  _Float16* rd = (_Float16*)&hA[0][0] + q * 8;   // afrag base (quad bcast)
  _Float16* wrh = (_Float16*)&hA[1][0] + col0;   // h write base (q==0)

  // prefetch x for t=0,1
  _Float16 xva[6], xvb[6];
  {
    const _Float16* p0 = xr0;
    const _Float16* p1 = xr0 + 768;
    xva[0] = p0[0];   xva[1] = p0[256]; xva[2] = p0[512];
    xva[3] = p0[128]; xva[4] = p0[384]; xva[5] = p0[640];
    xvb[0] = p1[0];   xvb[1] = p1[256]; xvb[2] = p1[512];
    xvb[3] = p1[128]; xvb[4] = p1[384]; xvb[5] = p1[640];
  }

  auto step = [&](_Float16* xv, bool prefetch) {
    // --- rec = h @ W_rec; afrag = quad-broadcast 16B reads, imm offsets
    f32x4_t acc[6];
#pragma unroll
    for (int i = 0; i < 6; ++i) acc[i] = (f32x4_t){0.f, 0.f, 0.f, 0.f};
#pragma unroll
    for (int kt = 0; kt < 8; ++kt) {
      f16x8_t afrag = *(const f16x8_t*)(rd + kt * 32);
#pragma unroll
      for (int i = 0; i < 6; ++i)
        acc[i] = __builtin_amdgcn_mfma_f32_16x16x32_f16(afrag, wfrag[i][kt],
                                                        acc[i], 0, 0, 0);
    }

    // --- gates (quads redundant; q==0 stores)
    float z0 = fast_sigmoid((float)xv[0] + acc[0][0]);
    float r0 = fast_sigmoid((float)xv[1] + acc[2][0]);
    float hc0 = fast_tanh((float)xv[2] + r0 * acc[4][0]);
    hold0 = hc0 + z0 * (hold0 - hc0);

    float z1 = fast_sigmoid((float)xv[3] + acc[1][0]);
    float r1 = fast_sigmoid((float)xv[4] + acc[3][0]);
    float hc1 = fast_tanh((float)xv[5] + r1 * acc[5][0]);
    hold1 = hc1 + z1 * (hold1 - hc1);

    if (q == 0) {
      orow[0] = hold0;    // fire-and-forget
      orow[128] = hold1;  // imm offset 512B
      wrh[0] = (_Float16)hold0;
      wrh[128] = (_Float16)hold1;
    }

    if (prefetch) {
      xv[0] = xr2[0];   xv[1] = xr2[256]; xv[2] = xr2[512];
      xv[3] = xr2[128]; xv[4] = xr2[384]; xv[5] = xr2[640];
      xr2 += 768;  // scalar-side bump
    }
    orow += 256;
    // ping-pong LDS buffers (single XOR on each byte address)
    rd = (_Float16*)((uintptr_t)rd ^ 512);
    wrh = (_Float16*)((uintptr_t)wrh ^ 512);

    sync_lds();  // LDS-only barrier; global ops stay in flight
  };

  for (int tt = 0; tt < 255; ++tt) {  // t = 0..509 with prefetch
    step(xva, true);
    step(xvb, true);
  }
  step(xva, false);  // t = 510
  step(xvb, false);  // t = 511

  // --- dense head: h_last (f16) is in hA[0] (512 steps -> buffer 0)
  if (tid < 64) {
    float acc = db[tid];
#pragma unroll 8
    for (int k = 0; k < 256; ++k)
      acc = fmaf((float)hA[0][k], dw[k * 64 + tid], acc);
    state[(size_t)b * 64 + tid] = fast_tanh(acc);
  }
}

// ---------------------------------------------------------------------------
extern "C" void kernel_launch(void* const* d_in, const int* in_sizes, int n_in,
                              void* d_out, int out_size, void* d_ws,
                              size_t ws_size, hipStream_t stream) {
  const float* x = (const float*)d_in[0];     // (64,512,64)
  const float* kmat = (const float*)d_in[1];  // (64,768)
  const float* wr = (const float*)d_in[2];    // (256,768)
  const float* bias = (const float*)d_in[3];  // (768,)
  const float* dw = (const float*)d_in[4];    // (256,64)
  const float* db = (const float*)d_in[5];    // (64,)

  float* out = (float*)d_out;                   // (64,512,256)
  float* state = out + (size_t)64 * 512 * 256;  // (64,64)
  _Float16* xp = (_Float16*)d_ws;               // 64*512*768 f16 = 48 MiB

  dim3 gg(32768 / 128, 768 / 128);
  xproj_gemm<<<gg, 256, 0, stream>>>(x, kmat, bias, xp);
  gru_scan_mfma<<<64, 512, 0, stream>>>(xp, wr, dw, db, out, state);
}